// Round 7
// baseline (1294.202 us; speedup 1.0000x reference)
//
#include <hip/hip_runtime.h>
#include <hip/hip_bf16.h>

#define NN 50000
#define EE 800000
#define DD 128
#define OVCAP 8192
#define LSTR 136
#define NTILE 1563      // (NN+31)/32
#define MGRID 1024      // persistent grid: 256 CU x 4 blocks/CU (residency by construction)
#define GS 4096         // gather wave stride = MGRID*4

typedef __attribute__((ext_vector_type(8))) short short8;
typedef __attribute__((ext_vector_type(4))) float floatx4;

__device__ __forceinline__ unsigned short f2bf(float f) {   // RNE
    unsigned int x = __float_as_uint(f);
    unsigned int r = x + 0x7fffu + ((x >> 16) & 1u);
    return (unsigned short)(r >> 16);
}
__device__ __forceinline__ float2 bf2x2(unsigned int u) {   // [lo,hi] bf16 pair
    return make_float2(__uint_as_float(u << 16), __uint_as_float(u & 0xffff0000u));
}

// ---- software grid barrier (agent scope: release on arrive, acquire on leave) --
// Leader resets count BEFORE bumping gen; gen is monotonic (replay-safe: count
// self-restores to 0, gen value is irrelevant, only change detection is used).
__device__ __forceinline__ void gsync(int* bc, int* bg) {
    __syncthreads();
    if (threadIdx.x == 0) {
        int g = __hip_atomic_load(bg, __ATOMIC_RELAXED, __HIP_MEMORY_SCOPE_AGENT);
        int a = __hip_atomic_fetch_add(bc, 1, __ATOMIC_ACQ_REL, __HIP_MEMORY_SCOPE_AGENT);
        if (a == MGRID - 1) {
            __hip_atomic_store(bc, 0, __ATOMIC_RELAXED, __HIP_MEMORY_SCOPE_AGENT);
            __hip_atomic_fetch_add(bg, 1, __ATOMIC_ACQ_REL, __HIP_MEMORY_SCOPE_AGENT);
        } else {
            while (__hip_atomic_load(bg, __ATOMIC_ACQUIRE, __HIP_MEMORY_SCOPE_AGENT) == g)
                __builtin_amdgcn_s_sleep(2);
        }
    }
    __syncthreads();
}

// ---------------- W prep (fragment order) + ELL all-pad init + all zeroing ------
__global__ void k_wprep(const float* __restrict__ conv_w, const float* __restrict__ mlp_w,
                        unsigned short* __restrict__ Wf, unsigned int* __restrict__ hsrow,
                        int* __restrict__ cnt, float* __restrict__ stats,
                        int* __restrict__ ovcnt, int* __restrict__ ell) {
    int g = blockIdx.x * 256 + threadIdx.x;
    if (g < 81920) {
        int m = g >> 14;
        int idx = g & 16383;
        int j  = idx & 7;
        int n  = (idx >> 3) & 15;
        int q  = (idx >> 7) & 3;
        int kk = (idx >> 9) & 3;
        int nt = (idx >> 11) & 1;
        int w  = (idx >> 12) & 3;
        int k = kk * 32 + q * 8 + j;
        int c = w * 32 + nt * 16 + n;
        const float* src = (m < 3) ? (conv_w + m * 16384) : (mlp_w + (m - 3) * 16384);
        Wf[g] = f2bf(src[k * 128 + c]);
    } else if (g < 81984) {
        hsrow[g - 81920] = 0u;                   // zero pad row HS[NN]
    } else if (g < 133184) {
        cnt[g - 81984] = 0;                      // zero degree/slot counters
    } else if (g < 133952) {
        stats[g - 133184] = 0.f;                 // zero cs3+css3 (768 floats)
    } else if (g < 133968) {
        ovcnt[g - 133952] = 0;                   // zero ovcnt + barrier counters (16 ints)
    } else if (g < 533968) {
        ((int4*)ell)[g - 133968] = make_int4(NN, NN, NN, NN);   // ELL = all pads
    }
}

// ------- XCD-team-filtered single-pass ELL build (no CSR, no scan) --------
__global__ void k_fill(const int* __restrict__ ei, int* __restrict__ cnt,
                       int* __restrict__ ell, int* __restrict__ ovcnt,
                       int2* __restrict__ ov) {
    const int team = blockIdx.x & 7;
    const int lo = team * 6250, hi = lo + 6250;
    const int tIdx = (blockIdx.x >> 3) * 256 + threadIdx.x;
    for (int e = tIdx; e < EE; e += 65536) {
        int d = ei[EE + e];
        if (d >= lo && d < hi) {
            int s = ei[e];
            if ((unsigned)s < (unsigned)NN) {
                int slot = atomicAdd(&cnt[d], 1);
                if (slot < 32) {
                    ell[d * 32 + slot] = s;
                } else {
                    int op = atomicAdd(ovcnt, 1);
                    if (op < OVCAP) ov[op] = make_int2(d, s);
                }
            }
        }
    }
}

// =================== persistent mega-kernel: 3×(gemm→gather) + mlp ==============
__global__ __launch_bounds__(256, 4) void k_mega(
        const float* __restrict__ xin, const int* __restrict__ cnt,
        const int* __restrict__ ell, const int2* __restrict__ ov,
        const int* __restrict__ ovcnt, const unsigned short* __restrict__ Wfb,
        const float* __restrict__ conv_b, const float* __restrict__ bn_g,
        const float* __restrict__ bn_b, const float* __restrict__ mlp_b,
        const float* __restrict__ out_w, const float* __restrict__ out_b,
        unsigned short* __restrict__ B0, unsigned short* __restrict__ B1b,
        float* __restrict__ cs3, float* __restrict__ css3,
        float* __restrict__ out, int* __restrict__ bc, int* __restrict__ bg) {
    __shared__ unsigned short Al[32 * LSTR];
    __shared__ float bnscL[128], bnshL[128];
    __shared__ float redH[4][32];
    __shared__ float redS[4][16][8];
    __shared__ float redQ[4][16][8];

    const int tid = threadIdx.x;
    const int lane = tid & 63;
    const int w = tid >> 6;
    const int oc = min(*ovcnt, OVCAP);
    const uint4* HSq = (const uint4*)B1b;

    for (int L = 0; L < 3; ++L) {
        // ================= GEMM phase: HS = pro(IN) @ W_L * rsqrt(cnt+1) =========
        {
            const bool pro = (L > 0);
            if (pro && tid < 128) {
                const float* cs = cs3 + (L - 1) * 128;
                const float* css = css3 + (L - 1) * 128;
                const float* gamma = bn_g + (L - 1) * DD;
                const float* beta = bn_b + (L - 1) * DD;
                const float invn = 1.f / (float)NN;
                float mean = cs[tid] * invn;
                float var = css[tid] * invn - mean * mean;
                float sc = gamma[tid] * rsqrtf(fmaxf(var, 0.f) + 1e-5f);
                bnscL[tid] = sc;
                bnshL[tid] = beta[tid] - mean * sc;
            }
            __syncthreads();

            short8 bf[2][4];
            {
                const uint4* Wq = (const uint4*)(Wfb + (size_t)L * 16384);
#pragma unroll
                for (int nt = 0; nt < 2; ++nt)
#pragma unroll
                    for (int kk = 0; kk < 4; ++kk) {
                        uint4 u = Wq[((w * 2 + nt) * 4 + kk) * 64 + lane];
                        bf[nt][kk] = *(short8*)&u;
                    }
            }
            const int n = lane & 15, q = lane >> 4;

            for (int t = blockIdx.x; t < NTILE; t += MGRID) {
                const int row0 = t * 32;
                {
                    int r = tid >> 3, ko8 = (tid & 7) * 16;
                    int gr = row0 + r;
                    unsigned short tmp[16];
                    if (!pro) {
#pragma unroll
                        for (int i = 0; i < 4; ++i) {
                            float4 v = make_float4(0.f, 0.f, 0.f, 0.f);
                            if (gr < NN) v = *(const float4*)&xin[(size_t)gr * DD + ko8 + i * 4];
                            tmp[i * 4 + 0] = f2bf(v.x); tmp[i * 4 + 1] = f2bf(v.y);
                            tmp[i * 4 + 2] = f2bf(v.z); tmp[i * 4 + 3] = f2bf(v.w);
                        }
                    } else {
                        const unsigned int* inu = (const unsigned int*)B0;
#pragma unroll
                        for (int i = 0; i < 2; ++i) {
                            uint4 u = make_uint4(0u, 0u, 0u, 0u);
                            if (gr < NN) u = *(const uint4*)&inu[(size_t)gr * 64 + (ko8 >> 1) + i * 4];
                            float2 p0 = bf2x2(u.x), p1 = bf2x2(u.y), p2 = bf2x2(u.z), p3 = bf2x2(u.w);
                            float vv[8] = {p0.x, p0.y, p1.x, p1.y, p2.x, p2.y, p3.x, p3.y};
#pragma unroll
                            for (int j = 0; j < 8; ++j) {
                                float t2 = fmaf(vv[j], bnscL[ko8 + i * 8 + j], bnshL[ko8 + i * 8 + j]);
                                tmp[i * 8 + j] = f2bf(fmaxf(t2, 0.f));
                            }
                        }
                    }
#pragma unroll
                    for (int j = 0; j < 2; ++j)
                        *(uint4*)&Al[r * LSTR + ko8 + j * 8] = ((uint4*)tmp)[j];
                }
                __syncthreads();

                floatx4 acc[2][2];
#pragma unroll
                for (int mt = 0; mt < 2; ++mt)
#pragma unroll
                    for (int nt = 0; nt < 2; ++nt)
                        acc[mt][nt] = (floatx4){0.f, 0.f, 0.f, 0.f};
#pragma unroll
                for (int kk = 0; kk < 4; ++kk) {
                    int ko = kk * 32 + q * 8;
#pragma unroll
                    for (int mt = 0; mt < 2; ++mt) {
                        short8 a = *(const short8*)&Al[(mt * 16 + n) * LSTR + ko];
                        acc[mt][0] = __builtin_amdgcn_mfma_f32_16x16x32_bf16(a, bf[0][kk], acc[mt][0], 0, 0, 0);
                        acc[mt][1] = __builtin_amdgcn_mfma_f32_16x16x32_bf16(a, bf[1][kk], acc[mt][1], 0, 0, 0);
                    }
                }
#pragma unroll
                for (int mt = 0; mt < 2; ++mt) {
#pragma unroll
                    for (int reg = 0; reg < 4; ++reg) {
                        int r = row0 + mt * 16 + q * 4 + reg;
                        if (r < NN) {
                            float sc = rsqrtf((float)cnt[r] + 1.0f);
                            B1b[(size_t)r * DD + w * 32 + n]      = f2bf(acc[mt][0][reg] * sc);
                            B1b[(size_t)r * DD + w * 32 + 16 + n] = f2bf(acc[mt][1][reg] * sc);
                        }
                    }
                }
                __syncthreads();   // protect Al for next tile
            }
        }
        gsync(bc, bg);

        // ================= gather phase (round-4 pipelined body) =================
        {
            const int c = lane & 15, jj = lane >> 4;
            const float* bias = conv_b + L * DD;
            const float4 bia0 = ((const float4*)bias)[2 * c];
            const float4 bia1 = ((const float4*)bias)[2 * c + 1];
            const bool relu = (L == 2);
            const uint4 z4 = make_uint4(0u, 0u, 0u, 0u);
            const int4 iz = make_int4(NN, NN, NN, NN);
            float sum[8], sq[8];
#pragma unroll
            for (int t = 0; t < 8; ++t) { sum[t] = 0.f; sq[t] = 0.f; }

            int r = blockIdx.x * 4 + w;
            int d = 0;
            int4 ia = iz, ib = iz;
            if (r < NN) {
                d = cnt[r];
                const int4* e4 = (const int4*)(ell + (size_t)r * 32);
                ia = e4[jj];
                ib = e4[jj + 4];
            }

            while (r < NN) {
                uint4 s0 = z4;
                if (jj == 0) s0 = HSq[(size_t)r * 16 + c];
                const bool pa = (ia.x != NN), pb = (ib.x != NN);
                uint4 va[4] = {z4, z4, z4, z4}, vb[4] = {z4, z4, z4, z4};
                if (pa) {
                    va[0] = HSq[(size_t)ia.x * 16 + c];
                    va[1] = HSq[(size_t)ia.y * 16 + c];
                    va[2] = HSq[(size_t)ia.z * 16 + c];
                    va[3] = HSq[(size_t)ia.w * 16 + c];
                }
                if (pb) {
                    vb[0] = HSq[(size_t)ib.x * 16 + c];
                    vb[1] = HSq[(size_t)ib.y * 16 + c];
                    vb[2] = HSq[(size_t)ib.z * 16 + c];
                    vb[3] = HSq[(size_t)ib.w * 16 + c];
                }

                const int rcur = r, dcur = d;

                r += GS;
                if (r < NN) {
                    d = cnt[r];
                    const int4* e4 = (const int4*)(ell + (size_t)r * 32);
                    ia = e4[jj];
                    ib = e4[jj + 4];
                } else {
                    ia = iz; ib = iz;
                }

                float a[8];
#pragma unroll
                for (int t = 0; t < 8; ++t) a[t] = 0.f;
                if (jj == 0) {
                    float2 p0 = bf2x2(s0.x), p1 = bf2x2(s0.y), p2 = bf2x2(s0.z), p3 = bf2x2(s0.w);
                    a[0] += p0.x; a[1] += p0.y; a[2] += p1.x; a[3] += p1.y;
                    a[4] += p2.x; a[5] += p2.y; a[6] += p3.x; a[7] += p3.y;
                }
                if (pa) {
#pragma unroll
                    for (int t = 0; t < 4; ++t) {
                        float2 p0 = bf2x2(va[t].x), p1 = bf2x2(va[t].y);
                        float2 p2 = bf2x2(va[t].z), p3 = bf2x2(va[t].w);
                        a[0] += p0.x; a[1] += p0.y; a[2] += p1.x; a[3] += p1.y;
                        a[4] += p2.x; a[5] += p2.y; a[6] += p3.x; a[7] += p3.y;
                    }
                }
                if (pb) {
#pragma unroll
                    for (int t = 0; t < 4; ++t) {
                        float2 p0 = bf2x2(vb[t].x), p1 = bf2x2(vb[t].y);
                        float2 p2 = bf2x2(vb[t].z), p3 = bf2x2(vb[t].w);
                        a[0] += p0.x; a[1] += p0.y; a[2] += p1.x; a[3] += p1.y;
                        a[4] += p2.x; a[5] += p2.y; a[6] += p3.x; a[7] += p3.y;
                    }
                }
                if (dcur > 32) {
                    for (int t = 0; t < oc; ++t) {
                        int2 e = ov[t];
                        if (jj == 0 && e.x == rcur) {
                            uint4 v = HSq[(size_t)e.y * 16 + c];
                            float2 p0 = bf2x2(v.x), p1 = bf2x2(v.y), p2 = bf2x2(v.z), p3 = bf2x2(v.w);
                            a[0] += p0.x; a[1] += p0.y; a[2] += p1.x; a[3] += p1.y;
                            a[4] += p2.x; a[5] += p2.y; a[6] += p3.x; a[7] += p3.y;
                        }
                    }
                }

#pragma unroll
                for (int t = 0; t < 8; ++t) {
                    a[t] += __shfl_xor(a[t], 16);
                    a[t] += __shfl_xor(a[t], 32);
                }

                if (jj == 0) {
                    float dr = rsqrtf((float)dcur + 1.0f);
                    float v[8];
                    v[0] = fmaf(dr, a[0], bia0.x); v[1] = fmaf(dr, a[1], bia0.y);
                    v[2] = fmaf(dr, a[2], bia0.z); v[3] = fmaf(dr, a[3], bia0.w);
                    v[4] = fmaf(dr, a[4], bia1.x); v[5] = fmaf(dr, a[5], bia1.y);
                    v[6] = fmaf(dr, a[6], bia1.z); v[7] = fmaf(dr, a[7], bia1.w);
                    if (relu) {
#pragma unroll
                        for (int t = 0; t < 8; ++t) v[t] = fmaxf(v[t], 0.f);
                    }
                    unsigned int p[4];
#pragma unroll
                    for (int t = 0; t < 4; ++t)
                        p[t] = (unsigned int)f2bf(v[2 * t]) | ((unsigned int)f2bf(v[2 * t + 1]) << 16);
                    *(uint4*)&B0[(size_t)rcur * DD + c * 8] = make_uint4(p[0], p[1], p[2], p[3]);
#pragma unroll
                    for (int t = 0; t < 8; ++t) { sum[t] += v[t]; sq[t] += v[t] * v[t]; }
                }
            }

            if (jj == 0) {
#pragma unroll
                for (int t = 0; t < 8; ++t) { redS[w][c][t] = sum[t]; redQ[w][c][t] = sq[t]; }
            }
            __syncthreads();
            if (tid < 128) {
                int ci = tid >> 3, ct = tid & 7;
                float S = (redS[0][ci][ct] + redS[1][ci][ct]) + (redS[2][ci][ct] + redS[3][ci][ct]);
                float Q = (redQ[0][ci][ct] + redQ[1][ci][ct]) + (redQ[2][ci][ct] + redQ[3][ci][ct]);
                atomicAdd(&cs3[L * 128 + tid], S);
                atomicAdd(&css3[L * 128 + tid], Q);
            }
        }
        gsync(bc, bg);
    }

    // ================= MLP + head phase =========================================
    {
        if (tid < 128) {
            const float* cs = cs3 + 256;
            const float* css = css3 + 256;
            const float* gamma = bn_g + DD;
            const float* beta = bn_b + DD;
            const float invn = 1.f / (float)NN;
            float mean = cs[tid] * invn;
            float var = css[tid] * invn - mean * mean;
            float sc = gamma[tid] * rsqrtf(fmaxf(var, 0.f) + 1e-5f);
            bnscL[tid] = sc;
            bnshL[tid] = beta[tid] - mean * sc;
        }
        __syncthreads();

        const int n = lane & 15, q = lane >> 4;
        const unsigned int* INu = (const unsigned int*)B0;
        const uint4* Wq4 = (const uint4*)(Wfb + 3 * 16384);
        const uint4* Wq5 = (const uint4*)(Wfb + 4 * 16384);
        const float b40 = mlp_b[w * 32 + n], b41 = mlp_b[w * 32 + 16 + n];
        const float b50 = mlp_b[DD + w * 32 + n], b51 = mlp_b[DD + w * 32 + 16 + n];
        const float w0c = out_w[w * 32 + n], w1c = out_w[w * 32 + 16 + n];

        for (int t = blockIdx.x; t < NTILE; t += MGRID) {
            const int row0 = t * 32;
            {
                int r = tid >> 3, ko8 = (tid & 7) * 16;
                int gr = row0 + r;
                unsigned short tmp[16];
#pragma unroll
                for (int i = 0; i < 2; ++i) {
                    uint4 u = make_uint4(0u, 0u, 0u, 0u);
                    if (gr < NN) u = *(const uint4*)&INu[(size_t)gr * 64 + (ko8 >> 1) + i * 4];
                    float2 p0 = bf2x2(u.x), p1 = bf2x2(u.y), p2 = bf2x2(u.z), p3 = bf2x2(u.w);
                    float vv[8] = {p0.x, p0.y, p1.x, p1.y, p2.x, p2.y, p3.x, p3.y};
#pragma unroll
                    for (int j = 0; j < 8; ++j) {
                        float t2 = fmaf(vv[j], bnscL[ko8 + i * 8 + j], bnshL[ko8 + i * 8 + j]);
                        tmp[i * 8 + j] = f2bf(t2);
                    }
                }
#pragma unroll
                for (int j = 0; j < 2; ++j)
                    *(uint4*)&Al[r * LSTR + ko8 + j * 8] = ((uint4*)tmp)[j];
            }
            __syncthreads();

            floatx4 acc[2][2];
#pragma unroll
            for (int mt = 0; mt < 2; ++mt)
#pragma unroll
                for (int nt = 0; nt < 2; ++nt)
                    acc[mt][nt] = (floatx4){0.f, 0.f, 0.f, 0.f};
#pragma unroll
            for (int kk = 0; kk < 4; ++kk) {
                uint4 u0 = Wq4[((w * 2 + 0) * 4 + kk) * 64 + lane];
                uint4 u1 = Wq4[((w * 2 + 1) * 4 + kk) * 64 + lane];
                int ko = kk * 32 + q * 8;
#pragma unroll
                for (int mt = 0; mt < 2; ++mt) {
                    short8 a = *(const short8*)&Al[(mt * 16 + n) * LSTR + ko];
                    acc[mt][0] = __builtin_amdgcn_mfma_f32_16x16x32_bf16(a, *(short8*)&u0, acc[mt][0], 0, 0, 0);
                    acc[mt][1] = __builtin_amdgcn_mfma_f32_16x16x32_bf16(a, *(short8*)&u1, acc[mt][1], 0, 0, 0);
                }
            }
            __syncthreads();
#pragma unroll
            for (int mt = 0; mt < 2; ++mt) {
#pragma unroll
                for (int reg = 0; reg < 4; ++reg) {
                    int r = mt * 16 + q * 4 + reg;
                    Al[r * LSTR + w * 32 + n]      = f2bf(fmaxf(acc[mt][0][reg] + b40, 0.f));
                    Al[r * LSTR + w * 32 + 16 + n] = f2bf(fmaxf(acc[mt][1][reg] + b41, 0.f));
                }
            }
            __syncthreads();
#pragma unroll
            for (int mt = 0; mt < 2; ++mt)
#pragma unroll
                for (int nt = 0; nt < 2; ++nt)
                    acc[mt][nt] = (floatx4){0.f, 0.f, 0.f, 0.f};
#pragma unroll
            for (int kk = 0; kk < 4; ++kk) {
                uint4 u0 = Wq5[((w * 2 + 0) * 4 + kk) * 64 + lane];
                uint4 u1 = Wq5[((w * 2 + 1) * 4 + kk) * 64 + lane];
                int ko = kk * 32 + q * 8;
#pragma unroll
                for (int mt = 0; mt < 2; ++mt) {
                    short8 a = *(const short8*)&Al[(mt * 16 + n) * LSTR + ko];
                    acc[mt][0] = __builtin_amdgcn_mfma_f32_16x16x32_bf16(a, *(short8*)&u0, acc[mt][0], 0, 0, 0);
                    acc[mt][1] = __builtin_amdgcn_mfma_f32_16x16x32_bf16(a, *(short8*)&u1, acc[mt][1], 0, 0, 0);
                }
            }
#pragma unroll
            for (int mt = 0; mt < 2; ++mt) {
#pragma unroll
                for (int reg = 0; reg < 4; ++reg) {
                    float h0 = fmaxf(acc[mt][0][reg] + b50, 0.f);
                    float h1 = fmaxf(acc[mt][1][reg] + b51, 0.f);
                    float p = fmaf(h0, w0c, h1 * w1c);
                    p += __shfl_xor(p, 1);
                    p += __shfl_xor(p, 2);
                    p += __shfl_xor(p, 4);
                    p += __shfl_xor(p, 8);
                    if (n == 0) redH[w][mt * 16 + q * 4 + reg] = p;
                }
            }
            __syncthreads();
            if (tid < 32) {
                int r = row0 + tid;
                if (r < NN) {
                    float z = (redH[0][tid] + redH[1][tid]) + (redH[2][tid] + redH[3][tid]) + out_b[0];
                    out[r] = 1.f / (1.f + expf(-z));
                }
            }
            __syncthreads();   // protect Al/redH for next tile
        }
    }
}

extern "C" void kernel_launch(void* const* d_in, const int* in_sizes, int n_in,
                              void* d_out, int out_size, void* d_ws, size_t ws_size,
                              hipStream_t stream) {
    const float* x      = (const float*)d_in[0];
    const int*   ei     = (const int*)d_in[1];
    const float* conv_w = (const float*)d_in[2];
    const float* conv_b = (const float*)d_in[3];
    const float* bn_g   = (const float*)d_in[4];
    const float* bn_b   = (const float*)d_in[5];
    const float* mlp_w  = (const float*)d_in[6];
    const float* mlp_b  = (const float*)d_in[7];
    const float* out_w  = (const float*)d_in[8];
    const float* out_b  = (const float*)d_in[9];
    float* out = (float*)d_out;

    const size_t ND4 = (size_t)NN * DD * 4;   // 25,600,000 B
    char* ws = (char*)d_ws;
    size_t off = 0;
    unsigned short* B0 = (unsigned short*)(ws + off); off += ND4 / 2;        // bf16 features
    unsigned short* B1b = (unsigned short*)(ws + off); off += ND4 / 2 + 256; // bf16 HS + pad row
    int*   cnt     = (int*)  (ws + off); off += 204800;             // degree/slot counters
    float* cs3     = (float*)(ws + off); off += 3 * 512;
    float* css3    = (float*)(ws + off); off += 3 * 512;
    int*   ovcnt   = (int*)  (ws + off); off += 64;                 // [0]=ovcnt, [8]=bar_cnt, [9]=bar_gen
    int2*  ov      = (int2*) (ws + off); off += OVCAP * 8;          // 64KB overflow list
    unsigned short* Wfb = (unsigned short*)(ws + off); off += 5 * 16384 * 2;
    int*   ell     = (int*)  (ws + off); off += (size_t)NN * 32 * 4;  // 6.4MB
    int* bc = ovcnt + 8;
    int* bg = ovcnt + 9;

    // wprep: weights (fragment order) + ELL all-pad init + zero cnt/stats/ovcnt/bar
    k_wprep<<<2086, 256, 0, stream>>>(conv_w, mlp_w, Wfb,
        (unsigned int*)(B1b + (size_t)NN * DD), cnt, cs3, ovcnt, ell);

    // XCD-team-filtered one-pass ELL build
    k_fill<<<2048, 256, 0, stream>>>(ei, cnt, ell, ovcnt, ov);

    // persistent fused pipeline: 3×(gemm→gather) + mlp_head with software barriers
    k_mega<<<MGRID, 256, 0, stream>>>(x, cnt, ell, ov, ovcnt, Wfb,
        conv_b, bn_g, bn_b, mlp_b, out_w, out_b, B0, B1b, cs3, css3, out, bc, bg);
}

// Round 8
// 370.239 us; speedup vs baseline: 3.4956x; 3.4956x over previous
//
#include <hip/hip_runtime.h>
#include <hip/hip_bf16.h>

#define NN 50000
#define EE 800000
#define DD 128
#define OVCAP 8192

typedef __attribute__((ext_vector_type(8))) short short8;
typedef __attribute__((ext_vector_type(4))) float floatx4;

__device__ __forceinline__ unsigned short f2bf(float f) {   // RNE
    unsigned int x = __float_as_uint(f);
    unsigned int r = x + 0x7fffu + ((x >> 16) & 1u);
    return (unsigned short)(r >> 16);
}
__device__ __forceinline__ float2 bf2x2(unsigned int u) {   // [lo,hi] bf16 pair
    return make_float2(__uint_as_float(u << 16), __uint_as_float(u & 0xffff0000u));
}

// ---------------- W prep (fragment order) + ELL all-pad init + all zeroing ------
__global__ void k_wprep(const float* __restrict__ conv_w, const float* __restrict__ mlp_w,
                        unsigned short* __restrict__ Wf, unsigned int* __restrict__ hsrow,
                        int* __restrict__ cnt, float* __restrict__ stats,
                        int* __restrict__ ovcnt, int* __restrict__ ell) {
    int g = blockIdx.x * 256 + threadIdx.x;
    if (g < 81920) {
        int m = g >> 14;
        int idx = g & 16383;
        int j  = idx & 7;
        int n  = (idx >> 3) & 15;
        int q  = (idx >> 7) & 3;
        int kk = (idx >> 9) & 3;
        int nt = (idx >> 11) & 1;
        int w  = (idx >> 12) & 3;
        int k = kk * 32 + q * 8 + j;
        int c = w * 32 + nt * 16 + n;
        const float* src = (m < 3) ? (conv_w + m * 16384) : (mlp_w + (m - 3) * 16384);
        Wf[g] = f2bf(src[k * 128 + c]);
    } else if (g < 81984) {
        hsrow[g - 81920] = 0u;                   // zero pad row HS[NN]
    } else if (g < 133184) {
        cnt[g - 81984] = 0;                      // zero degree/slot counters
    } else if (g < 133952) {
        stats[g - 133184] = 0.f;                 // zero cs3+css3 (768 floats)
    } else if (g < 133968) {
        ovcnt[g - 133952] = 0;                   // zero overflow counter
    } else if (g < 533968) {
        ((int4*)ell)[g - 133968] = make_int4(NN, NN, NN, NN);   // ELL = all pads
    }
}

// ------- XCD-team-filtered single-pass ELL build (no CSR, no scan) --------
__global__ void k_fill(const int* __restrict__ ei, int* __restrict__ cnt,
                       int* __restrict__ ell, int* __restrict__ ovcnt,
                       int2* __restrict__ ov) {
    const int team = blockIdx.x & 7;
    const int lo = team * 6250, hi = lo + 6250;
    const int tIdx = (blockIdx.x >> 3) * 256 + threadIdx.x;
    for (int e = tIdx; e < EE; e += 65536) {
        int d = ei[EE + e];
        if (d >= lo && d < hi) {
            int s = ei[e];
            if ((unsigned)s < (unsigned)NN) {
                int slot = atomicAdd(&cnt[d], 1);
                if (slot < 32) {
                    ell[d * 32 + slot] = s;
                } else {
                    int op = atomicAdd(ovcnt, 1);
                    if (op < OVCAP) ov[op] = make_int2(d, s);
                }
            }
        }
    }
}

// ---------------- conv MFMA GEMM: HS = pro(IN) @ W * rsqrt(cnt+1) -> bf16 -------
// Epilogue repacks acc through Al (LDS) and stores 2x dwordx4 per thread
// (256B contiguous per 8 threads) instead of 8 scattered 2B stores.
#define LSTR 136
template<int PRO>
__global__ __launch_bounds__(256) void k_gemm_conv(const void* __restrict__ INv,
                                                   const unsigned short* __restrict__ Wf,
                                                   const int* __restrict__ cnt,
                                                   const float* __restrict__ cs,
                                                   const float* __restrict__ css,
                                                   const float* __restrict__ gamma,
                                                   const float* __restrict__ beta,
                                                   unsigned short* __restrict__ OUT) {
    __shared__ unsigned short Al[32 * LSTR];    // 8.7KB
    __shared__ float bnscL[128], bnshL[128];
    const int tid = threadIdx.x;
    const int lane = tid & 63;
    const int w = tid >> 6;
    const int row0 = blockIdx.x * 32;

    if (PRO) {
        if (tid < 128) {
            const float invn = 1.f / (float)NN;
            float mean = cs[tid] * invn;
            float var = css[tid] * invn - mean * mean;
            float sc = gamma[tid] * rsqrtf(fmaxf(var, 0.f) + 1e-5f);
            bnscL[tid] = sc;
            bnshL[tid] = beta[tid] - mean * sc;
        }
        __syncthreads();
    }

    short8 bf[2][4];
    {
        const uint4* Wq = (const uint4*)Wf;
#pragma unroll
        for (int nt = 0; nt < 2; ++nt)
#pragma unroll
            for (int kk = 0; kk < 4; ++kk) {
                uint4 u = Wq[((w * 2 + nt) * 4 + kk) * 64 + lane];
                bf[nt][kk] = *(short8*)&u;
            }
    }

    // stage A: thread -> row tid>>3 (0..31), k-octant (tid&7)*16
    {
        int r = tid >> 3, ko8 = (tid & 7) * 16;
        int gr = row0 + r;
        unsigned short tmp[16];
        if (PRO == 0) {
            const float* IN = (const float*)INv;
#pragma unroll
            for (int i = 0; i < 4; ++i) {
                float4 v = make_float4(0.f, 0.f, 0.f, 0.f);
                if (gr < NN) v = *(const float4*)&IN[(size_t)gr * DD + ko8 + i * 4];
                tmp[i * 4 + 0] = f2bf(v.x); tmp[i * 4 + 1] = f2bf(v.y);
                tmp[i * 4 + 2] = f2bf(v.z); tmp[i * 4 + 3] = f2bf(v.w);
            }
        } else {
            const unsigned int* inu = (const unsigned int*)INv;
#pragma unroll
            for (int i = 0; i < 2; ++i) {
                uint4 u = make_uint4(0u, 0u, 0u, 0u);
                if (gr < NN) u = *(const uint4*)&inu[(size_t)gr * 64 + (ko8 >> 1) + i * 4];
                float2 p0 = bf2x2(u.x), p1 = bf2x2(u.y), p2 = bf2x2(u.z), p3 = bf2x2(u.w);
                float vv[8] = {p0.x, p0.y, p1.x, p1.y, p2.x, p2.y, p3.x, p3.y};
#pragma unroll
                for (int j = 0; j < 8; ++j) {
                    float t2 = fmaf(vv[j], bnscL[ko8 + i * 8 + j], bnshL[ko8 + i * 8 + j]);
                    tmp[i * 8 + j] = f2bf(fmaxf(t2, 0.f));
                }
            }
        }
#pragma unroll
        for (int j = 0; j < 2; ++j)
            *(uint4*)&Al[r * LSTR + ko8 + j * 8] = ((uint4*)tmp)[j];
    }
    __syncthreads();

    const int n = lane & 15, q = lane >> 4;
    floatx4 acc[2][2];
#pragma unroll
    for (int mt = 0; mt < 2; ++mt)
#pragma unroll
        for (int nt = 0; nt < 2; ++nt)
            acc[mt][nt] = (floatx4){0.f, 0.f, 0.f, 0.f};

#pragma unroll
    for (int kk = 0; kk < 4; ++kk) {
        int ko = kk * 32 + q * 8;
#pragma unroll
        for (int mt = 0; mt < 2; ++mt) {
            short8 a = *(const short8*)&Al[(mt * 16 + n) * LSTR + ko];
            acc[mt][0] = __builtin_amdgcn_mfma_f32_16x16x32_bf16(a, bf[0][kk], acc[mt][0], 0, 0, 0);
            acc[mt][1] = __builtin_amdgcn_mfma_f32_16x16x32_bf16(a, bf[1][kk], acc[mt][1], 0, 0, 0);
        }
    }
    __syncthreads();   // Al reads done; safe to overwrite with output repack

    // epilogue: scale, pack to bf16 in Al, then vectorized global stores
#pragma unroll
    for (int mt = 0; mt < 2; ++mt) {
#pragma unroll
        for (int reg = 0; reg < 4; ++reg) {
            int rr = mt * 16 + q * 4 + reg;
            int r = row0 + rr;
            float sc = 0.f;
            if (r < NN) sc = rsqrtf((float)cnt[r] + 1.0f);
            Al[rr * LSTR + w * 32 + n]      = f2bf(acc[mt][0][reg] * sc);
            Al[rr * LSTR + w * 32 + 16 + n] = f2bf(acc[mt][1][reg] * sc);
        }
    }
    __syncthreads();
    {
        int r = tid >> 3, ko8 = (tid & 7) * 16;
        int gr = row0 + r;
        if (gr < NN) {
            uint4 u0 = *(const uint4*)&Al[r * LSTR + ko8];
            uint4 u1 = *(const uint4*)&Al[r * LSTR + ko8 + 8];
            *(uint4*)&OUT[(size_t)gr * DD + ko8]     = u0;
            *(uint4*)&OUT[(size_t)gr * DD + ko8 + 8] = u1;
        }
    }
}

// ---------------- fused MLP + head (bf16 input, BN no relu), 32-row blocks ------
__global__ __launch_bounds__(256) void k_mlp_head(const unsigned int* __restrict__ INu,
                                                  const unsigned short* __restrict__ Wf4,
                                                  const unsigned short* __restrict__ Wf5,
                                                  const float* __restrict__ b4,
                                                  const float* __restrict__ b5,
                                                  const float* __restrict__ cs,
                                                  const float* __restrict__ css,
                                                  const float* __restrict__ gamma,
                                                  const float* __restrict__ beta,
                                                  const float* __restrict__ ow,
                                                  const float* __restrict__ ob,
                                                  float* __restrict__ out) {
    __shared__ unsigned short Al[32 * LSTR];
    __shared__ float bnscL[128], bnshL[128];
    __shared__ float redH[4][32];
    const int tid = threadIdx.x;
    const int lane = tid & 63;
    const int w = tid >> 6;
    const int row0 = blockIdx.x * 32;
    const int n = lane & 15, q = lane >> 4;

    if (tid < 128) {
        const float invn = 1.f / (float)NN;
        float mean = cs[tid] * invn;
        float var = css[tid] * invn - mean * mean;
        float sc = gamma[tid] * rsqrtf(fmaxf(var, 0.f) + 1e-5f);
        bnscL[tid] = sc;
        bnshL[tid] = beta[tid] - mean * sc;
    }
    __syncthreads();

    {
        int r = tid >> 3, ko8 = (tid & 7) * 16;
        int gr = row0 + r;
        unsigned short tmp[16];
#pragma unroll
        for (int i = 0; i < 2; ++i) {
            uint4 u = make_uint4(0u, 0u, 0u, 0u);
            if (gr < NN) u = *(const uint4*)&INu[(size_t)gr * 64 + (ko8 >> 1) + i * 4];
            float2 p0 = bf2x2(u.x), p1 = bf2x2(u.y), p2 = bf2x2(u.z), p3 = bf2x2(u.w);
            float vv[8] = {p0.x, p0.y, p1.x, p1.y, p2.x, p2.y, p3.x, p3.y};
#pragma unroll
            for (int j = 0; j < 8; ++j) {
                float t2 = fmaf(vv[j], bnscL[ko8 + i * 8 + j], bnshL[ko8 + i * 8 + j]);
                tmp[i * 8 + j] = f2bf(t2);
            }
        }
#pragma unroll
        for (int j = 0; j < 2; ++j)
            *(uint4*)&Al[r * LSTR + ko8 + j * 8] = ((uint4*)tmp)[j];
    }
    __syncthreads();

    floatx4 acc[2][2];
#pragma unroll
    for (int mt = 0; mt < 2; ++mt)
#pragma unroll
        for (int nt = 0; nt < 2; ++nt)
            acc[mt][nt] = (floatx4){0.f, 0.f, 0.f, 0.f};
    {
        const uint4* Wq = (const uint4*)Wf4;
#pragma unroll
        for (int kk = 0; kk < 4; ++kk) {
            uint4 u0 = Wq[((w * 2 + 0) * 4 + kk) * 64 + lane];
            uint4 u1 = Wq[((w * 2 + 1) * 4 + kk) * 64 + lane];
            int ko = kk * 32 + q * 8;
#pragma unroll
            for (int mt = 0; mt < 2; ++mt) {
                short8 a = *(const short8*)&Al[(mt * 16 + n) * LSTR + ko];
                acc[mt][0] = __builtin_amdgcn_mfma_f32_16x16x32_bf16(a, *(short8*)&u0, acc[mt][0], 0, 0, 0);
                acc[mt][1] = __builtin_amdgcn_mfma_f32_16x16x32_bf16(a, *(short8*)&u1, acc[mt][1], 0, 0, 0);
            }
        }
    }
    __syncthreads();

    {
        float b0c = b4[w * 32 + n], b1c = b4[w * 32 + 16 + n];
#pragma unroll
        for (int mt = 0; mt < 2; ++mt) {
#pragma unroll
            for (int reg = 0; reg < 4; ++reg) {
                int r = mt * 16 + q * 4 + reg;
                Al[r * LSTR + w * 32 + n]      = f2bf(fmaxf(acc[mt][0][reg] + b0c, 0.f));
                Al[r * LSTR + w * 32 + 16 + n] = f2bf(fmaxf(acc[mt][1][reg] + b1c, 0.f));
            }
        }
    }
    __syncthreads();

#pragma unroll
    for (int mt = 0; mt < 2; ++mt)
#pragma unroll
        for (int nt = 0; nt < 2; ++nt)
            acc[mt][nt] = (floatx4){0.f, 0.f, 0.f, 0.f};
    {
        const uint4* Wq = (const uint4*)Wf5;
#pragma unroll
        for (int kk = 0; kk < 4; ++kk) {
            uint4 u0 = Wq[((w * 2 + 0) * 4 + kk) * 64 + lane];
            uint4 u1 = Wq[((w * 2 + 1) * 4 + kk) * 64 + lane];
            int ko = kk * 32 + q * 8;
#pragma unroll
            for (int mt = 0; mt < 2; ++mt) {
                short8 a = *(const short8*)&Al[(mt * 16 + n) * LSTR + ko];
                acc[mt][0] = __builtin_amdgcn_mfma_f32_16x16x32_bf16(a, *(short8*)&u0, acc[mt][0], 0, 0, 0);
                acc[mt][1] = __builtin_amdgcn_mfma_f32_16x16x32_bf16(a, *(short8*)&u1, acc[mt][1], 0, 0, 0);
            }
        }
    }
    {
        float b0c = b5[w * 32 + n], b1c = b5[w * 32 + 16 + n];
        float w0c = ow[w * 32 + n], w1c = ow[w * 32 + 16 + n];
#pragma unroll
        for (int mt = 0; mt < 2; ++mt) {
#pragma unroll
            for (int reg = 0; reg < 4; ++reg) {
                float h0 = fmaxf(acc[mt][0][reg] + b0c, 0.f);
                float h1 = fmaxf(acc[mt][1][reg] + b1c, 0.f);
                float p = fmaf(h0, w0c, h1 * w1c);
                p += __shfl_xor(p, 1);
                p += __shfl_xor(p, 2);
                p += __shfl_xor(p, 4);
                p += __shfl_xor(p, 8);
                if (n == 0) redH[w][mt * 16 + q * 4 + reg] = p;
            }
        }
        __syncthreads();
        if (tid < 32) {
            int r = row0 + tid;
            if (r < NN) {
                float z = (redH[0][tid] + redH[1][tid]) + (redH[2][tid] + redH[3][tid]) + ob[0];
                out[r] = 1.f / (1.f + expf(-z));
            }
        }
    }
}
#undef LSTR

// ------ gather: 1-stage pipelined ELL; next row's cnt/ELL prefetched under ------
// the current row's HS-load wait. Pad-group predication via ia.x (dense fill
// => group jj all-pad iff ell[r*32+4*jj]==NN), so cnt is OFF the critical
// path (consumed only at the tail).
template<int RELU>
__global__ __launch_bounds__(256) void k_gather(const int* __restrict__ cnt,
                                                const int* __restrict__ ell,
                                                const int2* __restrict__ ov,
                                                const int* __restrict__ ovcnt,
                                                const uint4* __restrict__ HSq,
                                                const float* __restrict__ bias,
                                                unsigned short* __restrict__ OUT,
                                                float* __restrict__ colsum,
                                                float* __restrict__ colsumsq) {
    const int tid = threadIdx.x;
    const int lane = tid & 63;
    const int wid = tid >> 6;
    const int c = lane & 15;
    const int jj = lane >> 4;
    const int gwave = blockIdx.x * 4 + wid;
    const int oc = min(*ovcnt, OVCAP);

    float4 bia0 = ((const float4*)bias)[2 * c];
    float4 bia1 = ((const float4*)bias)[2 * c + 1];
    float sum[8], sq[8];
#pragma unroll
    for (int t = 0; t < 8; ++t) { sum[t] = 0.f; sq[t] = 0.f; }

    const uint4 z4 = make_uint4(0u, 0u, 0u, 0u);
    const int4 iz = make_int4(NN, NN, NN, NN);

    // prologue: metadata for first row
    int r = gwave;
    int d = 0;
    int4 ia = iz, ib = iz;
    if (r < NN) {
        d = cnt[r];
        const int4* e4 = (const int4*)(ell + (size_t)r * 32);
        ia = e4[jj];
        ib = e4[jj + 4];
    }

    while (r < NN) {
        // ---- issue all HS loads for the current row ----
        uint4 s0 = z4;
        if (jj == 0) s0 = HSq[(size_t)r * 16 + c];
        const bool pa = (ia.x != NN), pb = (ib.x != NN);
        uint4 va[4] = {z4, z4, z4, z4}, vb[4] = {z4, z4, z4, z4};
        if (pa) {
            va[0] = HSq[(size_t)ia.x * 16 + c];
            va[1] = HSq[(size_t)ia.y * 16 + c];
            va[2] = HSq[(size_t)ia.z * 16 + c];
            va[3] = HSq[(size_t)ia.w * 16 + c];
        }
        if (pb) {
            vb[0] = HSq[(size_t)ib.x * 16 + c];
            vb[1] = HSq[(size_t)ib.y * 16 + c];
            vb[2] = HSq[(size_t)ib.z * 16 + c];
            vb[3] = HSq[(size_t)ib.w * 16 + c];
        }

        const int rcur = r, dcur = d;

        // ---- prefetch next row's metadata (overlaps the HS wait) ----
        r += 8192;
        if (r < NN) {
            d = cnt[r];
            const int4* e4 = (const int4*)(ell + (size_t)r * 32);
            ia = e4[jj];
            ib = e4[jj + 4];
        } else {
            ia = iz; ib = iz;
        }

        // ---- unpack + reduce + store current row ----
        float a[8];
#pragma unroll
        for (int t = 0; t < 8; ++t) a[t] = 0.f;
        if (jj == 0) {
            float2 p0 = bf2x2(s0.x), p1 = bf2x2(s0.y), p2 = bf2x2(s0.z), p3 = bf2x2(s0.w);
            a[0] += p0.x; a[1] += p0.y; a[2] += p1.x; a[3] += p1.y;
            a[4] += p2.x; a[5] += p2.y; a[6] += p3.x; a[7] += p3.y;
        }
        if (pa) {
#pragma unroll
            for (int t = 0; t < 4; ++t) {
                float2 p0 = bf2x2(va[t].x), p1 = bf2x2(va[t].y);
                float2 p2 = bf2x2(va[t].z), p3 = bf2x2(va[t].w);
                a[0] += p0.x; a[1] += p0.y; a[2] += p1.x; a[3] += p1.y;
                a[4] += p2.x; a[5] += p2.y; a[6] += p3.x; a[7] += p3.y;
            }
        }
        if (pb) {
#pragma unroll
            for (int t = 0; t < 4; ++t) {
                float2 p0 = bf2x2(vb[t].x), p1 = bf2x2(vb[t].y);
                float2 p2 = bf2x2(vb[t].z), p3 = bf2x2(vb[t].w);
                a[0] += p0.x; a[1] += p0.y; a[2] += p1.x; a[3] += p1.y;
                a[4] += p2.x; a[5] += p2.y; a[6] += p3.x; a[7] += p3.y;
            }
        }
        if (dcur > 32) {   // rare heavy row: scan tiny overflow list (wave-uniform)
            for (int t = 0; t < oc; ++t) {
                int2 e = ov[t];
                if (jj == 0 && e.x == rcur) {
                    uint4 v = HSq[(size_t)e.y * 16 + c];
                    float2 p0 = bf2x2(v.x), p1 = bf2x2(v.y), p2 = bf2x2(v.z), p3 = bf2x2(v.w);
                    a[0] += p0.x; a[1] += p0.y; a[2] += p1.x; a[3] += p1.y;
                    a[4] += p2.x; a[5] += p2.y; a[6] += p3.x; a[7] += p3.y;
                }
            }
        }

#pragma unroll
        for (int t = 0; t < 8; ++t) {
            a[t] += __shfl_xor(a[t], 16);
            a[t] += __shfl_xor(a[t], 32);
        }

        if (jj == 0) {
            float dr = rsqrtf((float)dcur + 1.0f);
            float v[8];
            v[0] = fmaf(dr, a[0], bia0.x); v[1] = fmaf(dr, a[1], bia0.y);
            v[2] = fmaf(dr, a[2], bia0.z); v[3] = fmaf(dr, a[3], bia0.w);
            v[4] = fmaf(dr, a[4], bia1.x); v[5] = fmaf(dr, a[5], bia1.y);
            v[6] = fmaf(dr, a[6], bia1.z); v[7] = fmaf(dr, a[7], bia1.w);
            if (RELU) {
#pragma unroll
                for (int t = 0; t < 8; ++t) v[t] = fmaxf(v[t], 0.f);
            }
            unsigned int p[4];
#pragma unroll
            for (int t = 0; t < 4; ++t)
                p[t] = (unsigned int)f2bf(v[2 * t]) | ((unsigned int)f2bf(v[2 * t + 1]) << 16);
            *(uint4*)&OUT[(size_t)rcur * DD + c * 8] = make_uint4(p[0], p[1], p[2], p[3]);
#pragma unroll
            for (int t = 0; t < 8; ++t) { sum[t] += v[t]; sq[t] += v[t] * v[t]; }
        }
    }

    __shared__ float redS[4][16][8];
    __shared__ float redQ[4][16][8];
    if (jj == 0) {
#pragma unroll
        for (int t = 0; t < 8; ++t) { redS[wid][c][t] = sum[t]; redQ[wid][c][t] = sq[t]; }
    }
    __syncthreads();
    if (tid < 128) {
        int ci = tid >> 3, ct = tid & 7;
        float S = (redS[0][ci][ct] + redS[1][ci][ct]) + (redS[2][ci][ct] + redS[3][ci][ct]);
        float Q = (redQ[0][ci][ct] + redQ[1][ci][ct]) + (redQ[2][ci][ct] + redQ[3][ci][ct]);
        atomicAdd(&colsum[tid], S);
        atomicAdd(&colsumsq[tid], Q);
    }
}

extern "C" void kernel_launch(void* const* d_in, const int* in_sizes, int n_in,
                              void* d_out, int out_size, void* d_ws, size_t ws_size,
                              hipStream_t stream) {
    const float* x      = (const float*)d_in[0];
    const int*   ei     = (const int*)d_in[1];
    const float* conv_w = (const float*)d_in[2];
    const float* conv_b = (const float*)d_in[3];
    const float* bn_g   = (const float*)d_in[4];
    const float* bn_b   = (const float*)d_in[5];
    const float* mlp_w  = (const float*)d_in[6];
    const float* mlp_b  = (const float*)d_in[7];
    const float* out_w  = (const float*)d_in[8];
    const float* out_b  = (const float*)d_in[9];
    float* out = (float*)d_out;

    const size_t ND4 = (size_t)NN * DD * 4;   // 25,600,000 B
    char* ws = (char*)d_ws;
    size_t off = 0;
    unsigned short* B0 = (unsigned short*)(ws + off); off += ND4 / 2;        // bf16 features
    unsigned short* B1b = (unsigned short*)(ws + off); off += ND4 / 2 + 256; // bf16 HS + pad row
    int*   cnt     = (int*)  (ws + off); off += 204800;             // degree/slot counters
    float* cs3     = (float*)(ws + off); off += 3 * 512;
    float* css3    = (float*)(ws + off); off += 3 * 512;
    int*   ovcnt   = (int*)  (ws + off); off += 64;
    int2*  ov      = (int2*) (ws + off); off += OVCAP * 8;          // 64KB overflow list
    unsigned short* Wfb = (unsigned short*)(ws + off); off += 5 * 16384 * 2;
    int*   ell     = (int*)  (ws + off); off += (size_t)NN * 32 * 4;  // 6.4MB
    // total ≈ 33.3 MB

    const int gemm_grid = (NN + 31) / 32;     // 1563 blocks
    const int gather_grid = 2048;             // 8192 waves

    // wprep: weights (fragment order) + ELL all-pad init + zero cnt/stats/ovcnt
    k_wprep<<<2086, 256, 0, stream>>>(conv_w, mlp_w, Wfb,
        (unsigned int*)(B1b + (size_t)NN * DD), cnt, cs3, ovcnt, ell);

    // XCD-team-filtered one-pass ELL build
    k_fill<<<2048, 256, 0, stream>>>(ei, cnt, ell, ovcnt, ov);

    // ---- layer 0 ----
    k_gemm_conv<0><<<gemm_grid, 256, 0, stream>>>(x, Wfb, cnt,
        nullptr, nullptr, nullptr, nullptr, B1b);
    k_gather<0><<<gather_grid, 256, 0, stream>>>(cnt, ell, ov, ovcnt, (const uint4*)B1b, conv_b, B0, cs3, css3);

    // ---- layer 1 ----
    k_gemm_conv<1><<<gemm_grid, 256, 0, stream>>>(B0, Wfb + 16384, cnt,
        cs3, css3, bn_g, bn_b, B1b);
    k_gather<0><<<gather_grid, 256, 0, stream>>>(cnt, ell, ov, ovcnt, (const uint4*)B1b, conv_b + DD, B0, cs3 + 128, css3 + 128);

    // ---- layer 2 ----
    k_gemm_conv<1><<<gemm_grid, 256, 0, stream>>>(B0, Wfb + 2 * 16384, cnt,
        cs3 + 128, css3 + 128, bn_g + DD, bn_b + DD, B1b);
    k_gather<1><<<gather_grid, 256, 0, stream>>>(cnt, ell, ov, ovcnt, (const uint4*)B1b, conv_b + 2 * DD, B0, cs3 + 256, css3 + 256);

    // ---- fused MLP + head ----
    k_mlp_head<<<gemm_grid, 256, 0, stream>>>((const unsigned int*)B0, Wfb + 3 * 16384, Wfb + 4 * 16384,
        mlp_b, mlp_b + DD, cs3 + 256, css3 + 256, bn_g + DD, bn_b + DD, out_w, out_b, out);
}